// Round 8
// baseline (194.025 us; speedup 1.0000x reference)
//
#include <hip/hip_runtime.h>
#include <hip/hip_bf16.h>

typedef __attribute__((ext_vector_type(8))) __bf16 bf16x8;
typedef __attribute__((ext_vector_type(4))) __bf16 bf16x4;
typedef __attribute__((ext_vector_type(4))) float  f32x4;

#define S_LEN 2048
#define D_DIM 1024
#define NH    16
#define GK    1024
#define GN    1024

__device__ __forceinline__ float fast_exp2(float x) {
#if __has_builtin(__builtin_amdgcn_exp2f)
  return __builtin_amdgcn_exp2f(x);
#else
  return exp2f(x);
#endif
}

// async global->LDS, 16B per lane; HW scatters to wave-uniform-base + lane*16
__device__ __forceinline__ void gld_lds16(const void* g, void* l) {
  __builtin_amdgcn_global_load_lds(
      (const __attribute__((address_space(1))) unsigned int*)g,
      (__attribute__((address_space(3))) unsigned int*)l, 16, 0, 0);
}

// ---------------- fused fp32 -> bf16 cast, grid-stride ----------------
__global__ __launch_bounds__(256) void cast_all(
    const float* __restrict__ x,  const float* __restrict__ wq, const float* __restrict__ wk,
    const float* __restrict__ wv, const float* __restrict__ wo,
    __bf16* __restrict__ xb, __bf16* __restrict__ wqb, __bf16* __restrict__ wkb,
    __bf16* __restrict__ wvb, __bf16* __restrict__ wob)
{
  const int NTOT = 2 << 20;                      // 2M float4 chunks
  for (int i = blockIdx.x * 256 + threadIdx.x; i < NTOT; i += 1024 * 256) {
    const float* s; __bf16* d; int off;
    if (i < (1 << 20)) { s = x; d = xb; off = i; }
    else {
      const int j = i - (1 << 20);
      const int r = j >> 18; off = j & ((1 << 18) - 1);
      s = (r == 0) ? wq : (r == 1) ? wk : (r == 2) ? wv : wo;
      d = (r == 0) ? wqb : (r == 1) ? wkb : (r == 2) ? wvb : wob;
    }
    float4 v = ((const float4*)s)[off];
    bf16x4 o = { (__bf16)v.x, (__bf16)v.y, (__bf16)v.z, (__bf16)v.w };
    ((bf16x4*)d)[off] = o;
  }
}

// ---------------- QKV GEMM 64x128, BK=64, XCD-partitioned ----------------
__global__ __launch_bounds__(256, 6) void gemm_qkv(
    const __bf16* __restrict__ A,
    const __bf16* __restrict__ W0, const __bf16* __restrict__ W1, const __bf16* __restrict__ W2,
    __bf16* __restrict__ C0, __bf16* __restrict__ C1, __bf16* __restrict__ VtOut)
{
  const int bid = blockIdx.x;
  const int e = bid & 7, mg = e >> 1, ng = e & 1;
  const int q = bid >> 3;              // 0..191
  const int mode = q % 3;
  const int t = q / 3;                 // 0..63
  const int m0 = (mg * 16 + (t & 15)) * 64;
  const int n0 = (ng * 4 + (t >> 4)) * 128;
  const __bf16* Wm = (mode == 0) ? W0 : (mode == 1) ? W1 : W2;

  __shared__ __align__(16) __bf16 As[64 * 64];    //  8 KB
  __shared__ __align__(16) __bf16 Bs[128 * 64];   // 16 KB

  const int tid  = threadIdx.x;
  const int lane = tid & 63;
  const int w    = tid >> 6;
  const int wr   = w >> 1, wc = w & 1;
  const int lm   = lane & 15, qd = lane >> 4;

  const __bf16* ap[2]; int loA[2];
  #pragma unroll
  for (int j = 0; j < 2; j++) {
    const int c = tid + 256 * j;
    const int r = c >> 3, cpos = c & 7;
    ap[j] = A + (size_t)(m0 + r) * GK + (cpos ^ (r & 7)) * 8;
    loA[j] = c * 8;
  }
  const __bf16* bp[4]; int loB[4];
  #pragma unroll
  for (int j = 0; j < 4; j++) {
    const int c = tid + 256 * j;
    const int r = c >> 3, cpos = c & 7;
    bp[j] = Wm + (size_t)(n0 + r) * GK + (cpos ^ (r & 7)) * 8;
    loB[j] = c * 8;
  }

  const int sw = lm & 7;

  f32x4 zero = {0.f, 0.f, 0.f, 0.f};
  f32x4 acc[2][4];
  #pragma unroll
  for (int i = 0; i < 2; i++)
    #pragma unroll
    for (int j = 0; j < 4; j++) acc[i][j] = zero;

  for (int k0 = 0; k0 < GK; k0 += 64) {
    #pragma unroll
    for (int j = 0; j < 2; j++) gld_lds16(ap[j] + k0, &As[loA[j]]);
    #pragma unroll
    for (int j = 0; j < 4; j++) gld_lds16(bp[j] + k0, &Bs[loB[j]]);
    __syncthreads();
    #pragma unroll
    for (int half = 0; half < 2; half++) {
      const int cph = ((qd + 4 * half) ^ sw) * 8;
      bf16x8 af[2], bfv[4];
      #pragma unroll
      for (int i = 0; i < 2; i++) af[i]  = *(const bf16x8*)&As[(wr * 32 + i * 16 + lm) * 64 + cph];
      #pragma unroll
      for (int j = 0; j < 4; j++) bfv[j] = *(const bf16x8*)&Bs[(wc * 64 + j * 16 + lm) * 64 + cph];
      #pragma unroll
      for (int i = 0; i < 2; i++)
        #pragma unroll
        for (int j = 0; j < 4; j++)
          acc[i][j] = __builtin_amdgcn_mfma_f32_16x16x32_bf16(af[i], bfv[j], acc[i][j], 0, 0, 0);
    }
    __syncthreads();
  }

  if (mode < 2) {
    __bf16* C = (mode == 0) ? C0 : C1;
    #pragma unroll
    for (int i = 0; i < 2; i++) {
      const int row = m0 + wr * 32 + i * 16 + qd * 4;
      #pragma unroll
      for (int j = 0; j < 4; j++) {
        const int col = n0 + wc * 64 + j * 16 + lm;
        #pragma unroll
        for (int r = 0; r < 4; r++)
          C[(size_t)(row + r) * GN + col] = (__bf16)acc[i][j][r];
      }
    }
  } else {
    #pragma unroll
    for (int i = 0; i < 2; i++) {
      const int row = m0 + wr * 32 + i * 16 + qd * 4;    // token
      const int b = row >> 11, s = row & (S_LEN - 1);
      #pragma unroll
      for (int j = 0; j < 4; j++) {
        const int col = n0 + wc * 64 + j * 16 + lm;      // vdim
        const int h = col >> 6, d = col & 63;
        bf16x4 o = { (__bf16)acc[i][j][0], (__bf16)acc[i][j][1],
                     (__bf16)acc[i][j][2], (__bf16)acc[i][j][3] };
        *(bf16x4*)(VtOut + (((size_t)(b * NH + h) * 64 + d) * S_LEN + s)) = o;
      }
    }
  }
}

// ---------------- out-proj GEMM 64x128, BK=64, XCD-partitioned (fp32 out) ----------
__global__ __launch_bounds__(256, 6) void gemm_out64(
    const __bf16* __restrict__ A, const __bf16* __restrict__ Wm, float* __restrict__ C)
{
  const int bid = blockIdx.x;          // 512
  const int e = bid & 7, mg = e >> 1, ng = e & 1;
  const int q = bid >> 3;              // 0..63
  const int m0 = (mg * 16 + (q & 15)) * 64;
  const int n0 = (ng * 4 + (q >> 4)) * 128;

  __shared__ __align__(16) __bf16 As[64 * 64];    //  8 KB
  __shared__ __align__(16) __bf16 Bs[128 * 64];   // 16 KB

  const int tid  = threadIdx.x;
  const int lane = tid & 63;
  const int w    = tid >> 6;
  const int wr   = w >> 1, wc = w & 1;
  const int lm   = lane & 15, qd = lane >> 4;

  const __bf16* ap[2]; int loA[2];
  #pragma unroll
  for (int j = 0; j < 2; j++) {
    const int c = tid + 256 * j;
    const int r = c >> 3, cpos = c & 7;
    ap[j] = A + (size_t)(m0 + r) * GK + (cpos ^ (r & 7)) * 8;
    loA[j] = c * 8;
  }
  const __bf16* bp[4]; int loB[4];
  #pragma unroll
  for (int j = 0; j < 4; j++) {
    const int c = tid + 256 * j;
    const int r = c >> 3, cpos = c & 7;
    bp[j] = Wm + (size_t)(n0 + r) * GK + (cpos ^ (r & 7)) * 8;
    loB[j] = c * 8;
  }

  const int sw = lm & 7;

  f32x4 zero = {0.f, 0.f, 0.f, 0.f};
  f32x4 acc[2][4];
  #pragma unroll
  for (int i = 0; i < 2; i++)
    #pragma unroll
    for (int j = 0; j < 4; j++) acc[i][j] = zero;

  for (int k0 = 0; k0 < GK; k0 += 64) {
    #pragma unroll
    for (int j = 0; j < 2; j++) gld_lds16(ap[j] + k0, &As[loA[j]]);
    #pragma unroll
    for (int j = 0; j < 4; j++) gld_lds16(bp[j] + k0, &Bs[loB[j]]);
    __syncthreads();
    #pragma unroll
    for (int half = 0; half < 2; half++) {
      const int cph = ((qd + 4 * half) ^ sw) * 8;
      bf16x8 af[2], bfv[4];
      #pragma unroll
      for (int i = 0; i < 2; i++) af[i]  = *(const bf16x8*)&As[(wr * 32 + i * 16 + lm) * 64 + cph];
      #pragma unroll
      for (int j = 0; j < 4; j++) bfv[j] = *(const bf16x8*)&Bs[(wc * 64 + j * 16 + lm) * 64 + cph];
      #pragma unroll
      for (int i = 0; i < 2; i++)
        #pragma unroll
        for (int j = 0; j < 4; j++)
          acc[i][j] = __builtin_amdgcn_mfma_f32_16x16x32_bf16(af[i], bfv[j], acc[i][j], 0, 0, 0);
    }
    __syncthreads();
  }

  #pragma unroll
  for (int i = 0; i < 2; i++) {
    const int row = m0 + wr * 32 + i * 16 + qd * 4;
    #pragma unroll
    for (int j = 0; j < 4; j++) {
      const int col = n0 + wc * 64 + j * 16 + lm;
      #pragma unroll
      for (int r = 0; r < 4; r++)
        C[(size_t)(row + r) * GN + col] = acc[i][j][r];
    }
  }
}

// ---------------- RMSNorm + RoPE + head split (Q,K only; bf16 in) ----------------
__global__ __launch_bounds__(256) void norm_rope(
    const __bf16* __restrict__ Qf, const __bf16* __restrict__ Kf,
    const float* __restrict__ gain, const int* __restrict__ positions,
    const int* __restrict__ theta_p,
    __bf16* __restrict__ Qh, __bf16* __restrict__ Kh)
{
  const int row = blockIdx.x;             // b*S + s
  const int s = row & (S_LEN - 1), b = row >> 11;
  const int t = threadIdx.x, d0 = t * 4;

  const bf16x4 qv = *(const bf16x4*)(Qf + (size_t)row * D_DIM + d0);
  const bf16x4 kv = *(const bf16x4*)(Kf + (size_t)row * D_DIM + d0);
  const float q0 = (float)qv[0], q1 = (float)qv[1], q2 = (float)qv[2], q3 = (float)qv[3];
  const float k0 = (float)kv[0], k1 = (float)kv[1], k2 = (float)kv[2], k3 = (float)kv[3];

  float sq = q0 * q0 + q1 * q1 + q2 * q2 + q3 * q3;
  float sk = k0 * k0 + k1 * k1 + k2 * k2 + k3 * k3;
  #pragma unroll
  for (int off = 32; off; off >>= 1) { sq += __shfl_xor(sq, off); sk += __shfl_xor(sk, off); }
  __shared__ float red[8];
  const int lane = t & 63, wv = t >> 6;
  if (lane == 0) { red[wv] = sq; red[4 + wv] = sk; }
  __syncthreads();
  sq = red[0] + red[1] + red[2] + red[3];
  sk = red[4] + red[5] + red[6] + red[7];
  const float invq = rsqrtf(sq * (1.0f / 1024.0f) + 1e-5f);
  const float invk = rsqrtf(sk * (1.0f / 1024.0f) + 1e-5f);

  const float4 g = *(const float4*)(gain + d0);
  const float qn0 = q0 * invq * g.x, qn1 = q1 * invq * g.y;
  const float qn2 = q2 * invq * g.z, qn3 = q3 * invq * g.w;
  const float kn0 = k0 * invk * g.x, kn1 = k1 * invk * g.y;
  const float kn2 = k2 * invk * g.z, kn3 = k3 * invk * g.w;

  const float pos = (float)positions[s];
  const float th  = (float)theta_p[0];
  const int idx = d0 & 63, h = d0 >> 6, p0 = idx >> 1;
  const float lg32 = __log2f(th) * (1.0f / 32.0f);
  const float f0 = fast_exp2(-(float)p0 * lg32);
  const float f1 = fast_exp2(-(float)(p0 + 1) * lg32);
  float s0, cc0, s1, cc1;
  __sincosf(pos * f0, &s0, &cc0);
  __sincosf(pos * f1, &s1, &cc1);

  const float qe0 = qn0 * cc0 - qn1 * s0, qo0 = qn1 * cc0 + qn0 * s0;
  const float qe1 = qn2 * cc1 - qn3 * s1, qo1 = qn3 * cc1 + qn2 * s1;
  const float ke0 = kn0 * cc0 - kn1 * s0, ko0 = kn1 * cc0 + kn0 * s0;
  const float ke1 = kn2 * cc1 - kn3 * s1, ko1 = kn3 * cc1 + kn2 * s1;

  const size_t obase = ((size_t)((b * NH + h) * S_LEN + s)) * 64 + idx;
  bf16x4 qo = { (__bf16)qe0, (__bf16)qo0, (__bf16)qe1, (__bf16)qo1 };
  bf16x4 ko = { (__bf16)ke0, (__bf16)ko0, (__bf16)ke1, (__bf16)ko1 };
  *(bf16x4*)(Qh + obase) = qo;
  *(bf16x4*)(Kh + obase) = ko;
}

// ---------------- causal flash attention, 128-row Q-tiles ----------------
// 512 blocks, 48 KB LDS -> 3 blocks/CU. Each wave owns TWO 16-row Q-frags
// (sub0 rows base+w*16, sub1 +64): K/V staged once per k-tile serves 2x FLOPs,
// barrier count per unit work halved vs 64-row tiles. kt = 0..2qt+1; sub0 skips
// the final tile. Co-resident pair {bid, bid+256} -> qt {15-j, j} = 34 iters both.
__global__ __launch_bounds__(256, 3) void attn_fwd(
    const __bf16* __restrict__ Qh, const __bf16* __restrict__ Kh,
    const __bf16* __restrict__ Vt, __bf16* __restrict__ Ob)
{
  const int bid = blockIdx.x;
  const int g   = bid >> 5, gj = g & 7, gs = g >> 3;
  const int qt  = gs ? gj : 15 - gj;             // heavy first; pairs sum 34
  const int rr  = bid & 31;
  const int bh  = (rr & 7) * 4 + (rr >> 3);      // same-bh blocks -> same bid%8 (XCD)
  const int tid = threadIdx.x, lane = tid & 63, w = tid >> 6;
  const int lm = lane & 15, qd = lane >> 4;

  __shared__ __align__(16) __bf16 smem[8192 + 8192 + 8192];   // 48 KB
  __bf16* Ks = smem;                 // [2][4096]
  __bf16* Vs = smem + 8192;          // [2][4096]
  __bf16* Pw = smem + 16384 + w * 2048;          // per wave: [2 subs][1024]

  const int row0 = qt * 128 + w * 16;            // sub0; sub1 = +64
  const size_t qbase = (size_t)bh * S_LEN * 64;
  bf16x8 aq[2][2];
  #pragma unroll
  for (int s = 0; s < 2; s++) {
    const size_t qoff = qbase + (size_t)(row0 + s * 64 + lm) * 64;
    aq[s][0] = *(const bf16x8*)(Qh + qoff + qd * 8);
    aq[s][1] = *(const bf16x8*)(Qh + qoff + 32 + qd * 8);
  }

  const __bf16* Kb = Kh + (size_t)bh * S_LEN * 64;
  const __bf16* Vb = Vt + (size_t)bh * 64 * S_LEN;
  const int c0 = tid, c1 = 256 + tid;
  const int kr0 = c0 >> 3, kr1 = c1 >> 3;
  const int kg0 = ((c0 & 7) ^ (kr0 & 7)) * 8;
  const int kg1 = ((c1 & 7) ^ (kr1 & 7)) * 8;
  const int cpA = (qd ^ (lm & 7)) * 8;
  const int cpB = cpA ^ 32;

  auto stage = [&](int buf, int k0) {
    __bf16* Kd = Ks + buf * 4096;
    __bf16* Vd = Vs + buf * 4096;
    gld_lds16(Kb + (size_t)(k0 + kr0) * 64 + kg0, &Kd[c0 * 8]);
    gld_lds16(Kb + (size_t)(k0 + kr1) * 64 + kg1, &Kd[c1 * 8]);
    gld_lds16(Vb + (size_t)kr0 * S_LEN + k0 + kg0, &Vd[c0 * 8]);
    gld_lds16(Vb + (size_t)kr1 * S_LEN + k0 + kg1, &Vd[c1 * 8]);
  };

  const float SC2 = 0.125f * 1.44269504089f;   // 1/sqrt(64) * log2(e)
  const float OFF = 12.0f;                     // fixed exponent offset (cancels in norm)
  f32x4 zero = {0.f, 0.f, 0.f, 0.f};
  float l[2][4] = {{0.f,0.f,0.f,0.f},{0.f,0.f,0.f,0.f}};
  f32x4 o[2][4];
  #pragma unroll
  for (int s = 0; s < 2; s++)
    #pragma unroll
    for (int jb = 0; jb < 4; jb++) o[s][jb] = zero;

  stage(0, 0);

  const int ktmax = 2 * qt + 1;
  const int pxor = qd * 4;

  for (int kt = 0; kt <= ktmax; ++kt) {
    const int cur = kt & 1;
    __syncthreads();                 // buf[cur] staged; buf[cur^1] free
    if (kt < ktmax) stage(cur ^ 1, (kt + 1) * 64);

    const __bf16* Kc = Ks + cur * 4096;
    const __bf16* Vc = Vs + cur * 4096;
    const int k0 = kt * 64;

    #pragma unroll
    for (int s = 0; s < 2; s++) {
      if (s == 0 && kt > 2 * qt) continue;       // sub0 inactive on last tile
      const int rowg = row0 + s * 64 + qd * 4;
      const bool diag = (kt == 2 * qt + s);
      __bf16* Ps = Pw + s * 1024;

      float p[4][4];
      #pragma unroll
      for (int kb = 0; kb < 4; kb++) {
        const int krow = (kb * 16 + lm) * 64;
        const bf16x8 bk0 = *(const bf16x8*)&Kc[krow + cpA];
        const bf16x8 bk1 = *(const bf16x8*)&Kc[krow + cpB];
        f32x4 sc = zero;
        sc = __builtin_amdgcn_mfma_f32_16x16x32_bf16(aq[s][0], bk0, sc, 0, 0, 0);
        sc = __builtin_amdgcn_mfma_f32_16x16x32_bf16(aq[s][1], bk1, sc, 0, 0, 0);
        if (diag) {
          const int colg = k0 + kb * 16 + lm;
          #pragma unroll
          for (int r = 0; r < 4; r++) {
            const float e = fast_exp2(fmaf(sc[r], SC2, -OFF));
            p[kb][r] = (colg <= rowg + r) ? e : 0.f;
            l[s][r] += p[kb][r];
          }
        } else {
          #pragma unroll
          for (int r = 0; r < 4; r++) {
            p[kb][r] = fast_exp2(fmaf(sc[r], SC2, -OFF));
            l[s][r] += p[kb][r];
          }
        }
      }

      // P: C-layout -> LDS (stride-64, XOR-chunk swizzled) -> A-layout frags
      #pragma unroll
      for (int kb = 0; kb < 4; kb++) {
        const int cb = kb * 2 + (lm >> 3), wi = lm & 7;
        #pragma unroll
        for (int r = 0; r < 4; r++) {
          const int prow = pxor + r;
          Ps[prow * 64 + ((cb ^ (prow & 7)) << 3) + wi] = (__bf16)p[kb][r];
        }
      }

      const bf16x8 ap0 = *(const bf16x8*)&Ps[lm * 64 + cpA];
      const bf16x8 ap1 = *(const bf16x8*)&Ps[lm * 64 + cpB];
      #pragma unroll
      for (int jb = 0; jb < 4; jb++) {
        const int vrow = (jb * 16 + lm) * 64;
        const bf16x8 bv0 = *(const bf16x8*)&Vc[vrow + cpA];
        const bf16x8 bv1 = *(const bf16x8*)&Vc[vrow + cpB];
        o[s][jb] = __builtin_amdgcn_mfma_f32_16x16x32_bf16(ap1, bv1,
                   __builtin_amdgcn_mfma_f32_16x16x32_bf16(ap0, bv0, o[s][jb], 0, 0, 0), 0, 0, 0);
      }
    }
  }

  const int b = bh >> 4, h = bh & 15;
  #pragma unroll
  for (int s = 0; s < 2; s++) {
    const int rowg = row0 + s * 64 + qd * 4;
    #pragma unroll
    for (int r = 0; r < 4; r++) {
      float lr = l[s][r];
      #pragma unroll
      for (int off = 8; off; off >>= 1) lr += __shfl_xor(lr, off);
      const float inv = 1.0f / lr;
      const size_t base = ((size_t)(b * S_LEN + rowg + r)) * D_DIM + h * 64;
      #pragma unroll
      for (int jb = 0; jb < 4; jb++)
        Ob[base + jb * 16 + lm] = (__bf16)(o[s][jb][r] * inv);
    }
  }
}

extern "C" void kernel_launch(void* const* d_in, const int* in_sizes, int n_in,
                              void* d_out, int out_size, void* d_ws, size_t ws_size,
                              hipStream_t stream)
{
  (void)in_sizes; (void)n_in; (void)out_size; (void)ws_size;
  const float* x    = (const float*)d_in[0];
  const float* WQ   = (const float*)d_in[1];
  const float* WK   = (const float*)d_in[2];
  const float* WV   = (const float*)d_in[3];
  const float* WO   = (const float*)d_in[4];
  const float* gain = (const float*)d_in[5];
  const int* positions = (const int*)d_in[6];
  const int* theta     = (const int*)d_in[7];
  float* out = (float*)d_out;

  char* ws = (char*)d_ws;
  const size_t MB = 1024 * 1024;
  __bf16* xb  = (__bf16*)(ws + 0);        //  8 MB
  __bf16* WQb = (__bf16*)(ws + 8  * MB);  //  2 MB
  __bf16* WKb = (__bf16*)(ws + 10 * MB);  //  2 MB
  __bf16* WVb = (__bf16*)(ws + 12 * MB);  //  2 MB
  __bf16* WOb = (__bf16*)(ws + 14 * MB);  //  2 MB
  __bf16* Qfb = (__bf16*)(ws + 16 * MB);  //  8 MB  Q pre-norm bf16 [4096][1024]
  __bf16* Kfb = (__bf16*)(ws + 24 * MB);  //  8 MB
  __bf16* Vt  = (__bf16*)(ws + 32 * MB);  //  8 MB  [bh][64][s]  (direct from GEMM)
  __bf16* Qh  = (__bf16*)(ws + 40 * MB);  //  8 MB  [bh][s][64]
  __bf16* Kh  = (__bf16*)(ws + 48 * MB);  //  8 MB
  __bf16* Ob  = (__bf16*)(ws + 56 * MB);  //  8 MB  [b][s][1024]

  cast_all<<<1024, 256, 0, stream>>>(x, WQ, WK, WV, WO, xb, WQb, WKb, WVb, WOb);
  gemm_qkv<<<1536, 256, 0, stream>>>(xb, WQb, WKb, WVb, Qfb, Kfb, Vt);
  norm_rope<<<4096, 256, 0, stream>>>(Qfb, Kfb, gain, positions, theta, Qh, Kh);
  attn_fwd<<<512, 256, 0, stream>>>(Qh, Kh, Vt, Ob);
  gemm_out64<<<512, 256, 0, stream>>>(Ob, WOb, out);
}

// Round 9
// 183.134 us; speedup vs baseline: 1.0595x; 1.0595x over previous
//
#include <hip/hip_runtime.h>
#include <hip/hip_bf16.h>

typedef __attribute__((ext_vector_type(8))) __bf16 bf16x8;
typedef __attribute__((ext_vector_type(4))) __bf16 bf16x4;
typedef __attribute__((ext_vector_type(4))) float  f32x4;

#define S_LEN 2048
#define D_DIM 1024
#define NH    16
#define GK    1024
#define GN    1024

__device__ __forceinline__ float fast_exp2(float x) {
#if __has_builtin(__builtin_amdgcn_exp2f)
  return __builtin_amdgcn_exp2f(x);
#else
  return exp2f(x);
#endif
}

// async global->LDS, 16B per lane; HW scatters to wave-uniform-base + lane*16
__device__ __forceinline__ void gld_lds16(const void* g, void* l) {
  __builtin_amdgcn_global_load_lds(
      (const __attribute__((address_space(1))) unsigned int*)g,
      (__attribute__((address_space(3))) unsigned int*)l, 16, 0, 0);
}

// ---------------- fused fp32 -> bf16 cast, grid-stride ----------------
__global__ __launch_bounds__(256) void cast_all(
    const float* __restrict__ x,  const float* __restrict__ wq, const float* __restrict__ wk,
    const float* __restrict__ wv, const float* __restrict__ wo,
    __bf16* __restrict__ xb, __bf16* __restrict__ wqb, __bf16* __restrict__ wkb,
    __bf16* __restrict__ wvb, __bf16* __restrict__ wob)
{
  const int NTOT = 2 << 20;                      // 2M float4 chunks
  for (int i = blockIdx.x * 256 + threadIdx.x; i < NTOT; i += 1024 * 256) {
    const float* s; __bf16* d; int off;
    if (i < (1 << 20)) { s = x; d = xb; off = i; }
    else {
      const int j = i - (1 << 20);
      const int r = j >> 18; off = j & ((1 << 18) - 1);
      s = (r == 0) ? wq : (r == 1) ? wk : (r == 2) ? wv : wo;
      d = (r == 0) ? wqb : (r == 1) ? wkb : (r == 2) ? wvb : wob;
    }
    float4 v = ((const float4*)s)[off];
    bf16x4 o = { (__bf16)v.x, (__bf16)v.y, (__bf16)v.z, (__bf16)v.w };
    ((bf16x4*)d)[off] = o;
  }
}

// ---------------- QKV GEMM 64x128, BK=64, XCD-partitioned ----------------
__global__ __launch_bounds__(256, 6) void gemm_qkv(
    const __bf16* __restrict__ A,
    const __bf16* __restrict__ W0, const __bf16* __restrict__ W1, const __bf16* __restrict__ W2,
    __bf16* __restrict__ C0, __bf16* __restrict__ C1, __bf16* __restrict__ VtOut)
{
  const int bid = blockIdx.x;
  const int e = bid & 7, mg = e >> 1, ng = e & 1;
  const int q = bid >> 3;              // 0..191
  const int mode = q % 3;
  const int t = q / 3;                 // 0..63
  const int m0 = (mg * 16 + (t & 15)) * 64;
  const int n0 = (ng * 4 + (t >> 4)) * 128;
  const __bf16* Wm = (mode == 0) ? W0 : (mode == 1) ? W1 : W2;

  __shared__ __align__(16) __bf16 As[64 * 64];    //  8 KB
  __shared__ __align__(16) __bf16 Bs[128 * 64];   // 16 KB

  const int tid  = threadIdx.x;
  const int lane = tid & 63;
  const int w    = tid >> 6;
  const int wr   = w >> 1, wc = w & 1;
  const int lm   = lane & 15, qd = lane >> 4;

  const __bf16* ap[2]; int loA[2];
  #pragma unroll
  for (int j = 0; j < 2; j++) {
    const int c = tid + 256 * j;
    const int r = c >> 3, cpos = c & 7;
    ap[j] = A + (size_t)(m0 + r) * GK + (cpos ^ (r & 7)) * 8;
    loA[j] = c * 8;
  }
  const __bf16* bp[4]; int loB[4];
  #pragma unroll
  for (int j = 0; j < 4; j++) {
    const int c = tid + 256 * j;
    const int r = c >> 3, cpos = c & 7;
    bp[j] = Wm + (size_t)(n0 + r) * GK + (cpos ^ (r & 7)) * 8;
    loB[j] = c * 8;
  }

  const int sw = lm & 7;

  f32x4 zero = {0.f, 0.f, 0.f, 0.f};
  f32x4 acc[2][4];
  #pragma unroll
  for (int i = 0; i < 2; i++)
    #pragma unroll
    for (int j = 0; j < 4; j++) acc[i][j] = zero;

  for (int k0 = 0; k0 < GK; k0 += 64) {
    #pragma unroll
    for (int j = 0; j < 2; j++) gld_lds16(ap[j] + k0, &As[loA[j]]);
    #pragma unroll
    for (int j = 0; j < 4; j++) gld_lds16(bp[j] + k0, &Bs[loB[j]]);
    __syncthreads();
    #pragma unroll
    for (int half = 0; half < 2; half++) {
      const int cph = ((qd + 4 * half) ^ sw) * 8;
      bf16x8 af[2], bfv[4];
      #pragma unroll
      for (int i = 0; i < 2; i++) af[i]  = *(const bf16x8*)&As[(wr * 32 + i * 16 + lm) * 64 + cph];
      #pragma unroll
      for (int j = 0; j < 4; j++) bfv[j] = *(const bf16x8*)&Bs[(wc * 64 + j * 16 + lm) * 64 + cph];
      #pragma unroll
      for (int i = 0; i < 2; i++)
        #pragma unroll
        for (int j = 0; j < 4; j++)
          acc[i][j] = __builtin_amdgcn_mfma_f32_16x16x32_bf16(af[i], bfv[j], acc[i][j], 0, 0, 0);
    }
    __syncthreads();
  }

  if (mode < 2) {
    __bf16* C = (mode == 0) ? C0 : C1;
    #pragma unroll
    for (int i = 0; i < 2; i++) {
      const int row = m0 + wr * 32 + i * 16 + qd * 4;
      #pragma unroll
      for (int j = 0; j < 4; j++) {
        const int col = n0 + wc * 64 + j * 16 + lm;
        #pragma unroll
        for (int r = 0; r < 4; r++)
          C[(size_t)(row + r) * GN + col] = (__bf16)acc[i][j][r];
      }
    }
  } else {
    #pragma unroll
    for (int i = 0; i < 2; i++) {
      const int row = m0 + wr * 32 + i * 16 + qd * 4;    // token
      const int b = row >> 11, s = row & (S_LEN - 1);
      #pragma unroll
      for (int j = 0; j < 4; j++) {
        const int col = n0 + wc * 64 + j * 16 + lm;      // vdim
        const int h = col >> 6, d = col & 63;
        bf16x4 o = { (__bf16)acc[i][j][0], (__bf16)acc[i][j][1],
                     (__bf16)acc[i][j][2], (__bf16)acc[i][j][3] };
        *(bf16x4*)(VtOut + (((size_t)(b * NH + h) * 64 + d) * S_LEN + s)) = o;
      }
    }
  }
}

// ---------------- out-proj GEMM 32x128, BK=64, XCD-partitioned (fp32 out) ----------
// 1024 blocks = 4/CU (grid-limited; LDS 20 KB would allow 8). Each wave owns a
// 32-col n-strip, acc[2][2]. Fixes the 2-blocks/CU latency exposure of 64x128.
__global__ __launch_bounds__(256, 4) void gemm_out32(
    const __bf16* __restrict__ A, const __bf16* __restrict__ Wm, float* __restrict__ C)
{
  const int bid = blockIdx.x;          // 1024
  const int e = bid & 7, mg = e >> 1, ng = e & 1;
  const int q = bid >> 3;              // 0..127
  const int m0 = (mg * 32 + (q & 31)) * 32;      // 128 m-tiles of 32 rows
  const int n0 = (ng * 4 + (q >> 5)) * 128;      // 8 n-strips of 128 cols

  __shared__ __align__(16) __bf16 As[32 * 64];    //  4 KB
  __shared__ __align__(16) __bf16 Bs[128 * 64];   // 16 KB

  const int tid  = threadIdx.x;
  const int lane = tid & 63;
  const int w    = tid >> 6;
  const int lm   = lane & 15, qd = lane >> 4;

  // A: 256 chunks (1/thread); B: 1024 chunks (4/thread)
  const int ca = tid, ra = ca >> 3;
  const __bf16* ap = A + (size_t)(m0 + ra) * GK + ((ca & 7) ^ (ra & 7)) * 8;
  const int loA = ca * 8;
  const __bf16* bp[4]; int loB[4];
  #pragma unroll
  for (int j = 0; j < 4; j++) {
    const int c = tid + 256 * j;
    const int r = c >> 3, cpos = c & 7;
    bp[j] = Wm + (size_t)(n0 + r) * GK + (cpos ^ (r & 7)) * 8;
    loB[j] = c * 8;
  }

  const int sw = lm & 7;

  f32x4 zero = {0.f, 0.f, 0.f, 0.f};
  f32x4 acc[2][2];
  #pragma unroll
  for (int i = 0; i < 2; i++)
    #pragma unroll
    for (int j = 0; j < 2; j++) acc[i][j] = zero;

  for (int k0 = 0; k0 < GK; k0 += 64) {
    gld_lds16(ap + k0, &As[loA]);
    #pragma unroll
    for (int j = 0; j < 4; j++) gld_lds16(bp[j] + k0, &Bs[loB[j]]);
    __syncthreads();
    #pragma unroll
    for (int half = 0; half < 2; half++) {
      const int cph = ((qd + 4 * half) ^ sw) * 8;
      bf16x8 af[2], bfv[2];
      #pragma unroll
      for (int i = 0; i < 2; i++) af[i]  = *(const bf16x8*)&As[(i * 16 + lm) * 64 + cph];
      #pragma unroll
      for (int j = 0; j < 2; j++) bfv[j] = *(const bf16x8*)&Bs[(w * 32 + j * 16 + lm) * 64 + cph];
      #pragma unroll
      for (int i = 0; i < 2; i++)
        #pragma unroll
        for (int j = 0; j < 2; j++)
          acc[i][j] = __builtin_amdgcn_mfma_f32_16x16x32_bf16(af[i], bfv[j], acc[i][j], 0, 0, 0);
    }
    __syncthreads();
  }

  #pragma unroll
  for (int i = 0; i < 2; i++) {
    const int row = m0 + i * 16 + qd * 4;
    #pragma unroll
    for (int j = 0; j < 2; j++) {
      const int col = n0 + w * 32 + j * 16 + lm;
      #pragma unroll
      for (int r = 0; r < 4; r++)
        C[(size_t)(row + r) * GN + col] = acc[i][j][r];
    }
  }
}

// ---------------- RMSNorm + RoPE + head split (Q,K only; bf16 in) ----------------
__global__ __launch_bounds__(256) void norm_rope(
    const __bf16* __restrict__ Qf, const __bf16* __restrict__ Kf,
    const float* __restrict__ gain, const int* __restrict__ positions,
    const int* __restrict__ theta_p,
    __bf16* __restrict__ Qh, __bf16* __restrict__ Kh)
{
  const int row = blockIdx.x;             // b*S + s
  const int s = row & (S_LEN - 1), b = row >> 11;
  const int t = threadIdx.x, d0 = t * 4;

  const bf16x4 qv = *(const bf16x4*)(Qf + (size_t)row * D_DIM + d0);
  const bf16x4 kv = *(const bf16x4*)(Kf + (size_t)row * D_DIM + d0);
  const float q0 = (float)qv[0], q1 = (float)qv[1], q2 = (float)qv[2], q3 = (float)qv[3];
  const float k0 = (float)kv[0], k1 = (float)kv[1], k2 = (float)kv[2], k3 = (float)kv[3];

  float sq = q0 * q0 + q1 * q1 + q2 * q2 + q3 * q3;
  float sk = k0 * k0 + k1 * k1 + k2 * k2 + k3 * k3;
  #pragma unroll
  for (int off = 32; off; off >>= 1) { sq += __shfl_xor(sq, off); sk += __shfl_xor(sk, off); }
  __shared__ float red[8];
  const int lane = t & 63, wv = t >> 6;
  if (lane == 0) { red[wv] = sq; red[4 + wv] = sk; }
  __syncthreads();
  sq = red[0] + red[1] + red[2] + red[3];
  sk = red[4] + red[5] + red[6] + red[7];
  const float invq = rsqrtf(sq * (1.0f / 1024.0f) + 1e-5f);
  const float invk = rsqrtf(sk * (1.0f / 1024.0f) + 1e-5f);

  const float4 g = *(const float4*)(gain + d0);
  const float qn0 = q0 * invq * g.x, qn1 = q1 * invq * g.y;
  const float qn2 = q2 * invq * g.z, qn3 = q3 * invq * g.w;
  const float kn0 = k0 * invk * g.x, kn1 = k1 * invk * g.y;
  const float kn2 = k2 * invk * g.z, kn3 = k3 * invk * g.w;

  const float pos = (float)positions[s];
  const float th  = (float)theta_p[0];
  const int idx = d0 & 63, h = d0 >> 6, p0 = idx >> 1;
  const float lg32 = __log2f(th) * (1.0f / 32.0f);
  const float f0 = fast_exp2(-(float)p0 * lg32);
  const float f1 = fast_exp2(-(float)(p0 + 1) * lg32);
  float s0, cc0, s1, cc1;
  __sincosf(pos * f0, &s0, &cc0);
  __sincosf(pos * f1, &s1, &cc1);

  const float qe0 = qn0 * cc0 - qn1 * s0, qo0 = qn1 * cc0 + qn0 * s0;
  const float qe1 = qn2 * cc1 - qn3 * s1, qo1 = qn3 * cc1 + qn2 * s1;
  const float ke0 = kn0 * cc0 - kn1 * s0, ko0 = kn1 * cc0 + kn0 * s0;
  const float ke1 = kn2 * cc1 - kn3 * s1, ko1 = kn3 * cc1 + kn2 * s1;

  const size_t obase = ((size_t)((b * NH + h) * S_LEN + s)) * 64 + idx;
  bf16x4 qo = { (__bf16)qe0, (__bf16)qo0, (__bf16)qe1, (__bf16)qo1 };
  bf16x4 ko = { (__bf16)ke0, (__bf16)ko0, (__bf16)ke1, (__bf16)ko1 };
  *(bf16x4*)(Qh + obase) = qo;
  *(bf16x4*)(Kh + obase) = ko;
}

// ---------------- causal flash attention, 1024 blocks @ 4/CU (R6 version) ----------
__global__ __launch_bounds__(256) void attn_fwd(
    const __bf16* __restrict__ Qh, const __bf16* __restrict__ Kh,
    const __bf16* __restrict__ Vt, __bf16* __restrict__ Ob)
{
  const int bid = blockIdx.x;
  const int g   = bid >> 5, gj = g & 7, gs = g >> 3;
  const int qt  = (gs == 0) ? 31 - gj : (gs == 1) ? gj : (gs == 2) ? 23 - gj : 8 + gj;
  const int rr  = bid & 31;
  const int bh  = (rr & 7) * 4 + (rr >> 3);      // same-bh blocks -> same bid%8 (XCD)
  const int tid = threadIdx.x, lane = tid & 63, w = tid >> 6;
  const int lm = lane & 15, qd = lane >> 4;

  __shared__ __align__(16) __bf16 smem[8192 + 8192 + 4096];   // 40960 B
  __bf16* Ks = smem;                 // [2][4096]
  __bf16* Vs = smem + 8192;          // [2][4096]
  __bf16* Pw = smem + 16384 + w * 1024;

  const int row0 = qt * 64 + w * 16;
  const size_t qbase = (size_t)bh * S_LEN * 64;
  const bf16x8 aq0 = *(const bf16x8*)(Qh + qbase + (size_t)(row0 + lm) * 64 + qd * 8);
  const bf16x8 aq1 = *(const bf16x8*)(Qh + qbase + (size_t)(row0 + lm) * 64 + 32 + qd * 8);

  const __bf16* Kb = Kh + (size_t)bh * S_LEN * 64;
  const __bf16* Vb = Vt + (size_t)bh * 64 * S_LEN;
  const int c0 = tid, c1 = 256 + tid;
  const int kr0 = c0 >> 3, kr1 = c1 >> 3;
  const int kg0 = ((c0 & 7) ^ (kr0 & 7)) * 8;
  const int kg1 = ((c1 & 7) ^ (kr1 & 7)) * 8;
  const int cpA = (qd ^ (lm & 7)) * 8;
  const int cpB = cpA ^ 32;

  auto stage = [&](int buf, int k0) {
    __bf16* Kd = Ks + buf * 4096;
    __bf16* Vd = Vs + buf * 4096;
    gld_lds16(Kb + (size_t)(k0 + kr0) * 64 + kg0, &Kd[c0 * 8]);
    gld_lds16(Kb + (size_t)(k0 + kr1) * 64 + kg1, &Kd[c1 * 8]);
    gld_lds16(Vb + (size_t)kr0 * S_LEN + k0 + kg0, &Vd[c0 * 8]);
    gld_lds16(Vb + (size_t)kr1 * S_LEN + k0 + kg1, &Vd[c1 * 8]);
  };

  const float SC2 = 0.125f * 1.44269504089f;   // 1/sqrt(64) * log2(e)
  const float OFF = 12.0f;                     // fixed exponent offset (cancels in norm)
  f32x4 zero = {0.f, 0.f, 0.f, 0.f};
  float l[4] = {0.f, 0.f, 0.f, 0.f};
  f32x4 o[4];
  #pragma unroll
  for (int jb = 0; jb < 4; jb++) o[jb] = zero;

  stage(0, 0);

  const int rowg = row0 + qd * 4;
  const int pxor = qd * 4;

  for (int kt = 0; kt <= qt; ++kt) {
    const int cur = kt & 1;
    __syncthreads();                 // buf[cur] staged; buf[cur^1] free
    if (kt < qt) stage(cur ^ 1, (kt + 1) * 64);

    const __bf16* Kc = Ks + cur * 4096;
    const __bf16* Vc = Vs + cur * 4096;
    const int k0 = kt * 64;

    float p[4][4];
    const bool diag = (kt == qt);
    #pragma unroll
    for (int kb = 0; kb < 4; kb++) {
      const int krow = (kb * 16 + lm) * 64;
      const bf16x8 bk0 = *(const bf16x8*)&Kc[krow + cpA];
      const bf16x8 bk1 = *(const bf16x8*)&Kc[krow + cpB];
      f32x4 sc = zero;
      sc = __builtin_amdgcn_mfma_f32_16x16x32_bf16(aq0, bk0, sc, 0, 0, 0);
      sc = __builtin_amdgcn_mfma_f32_16x16x32_bf16(aq1, bk1, sc, 0, 0, 0);
      if (diag) {
        const int colg = k0 + kb * 16 + lm;
        #pragma unroll
        for (int r = 0; r < 4; r++) {
          const float e = fast_exp2(fmaf(sc[r], SC2, -OFF));
          p[kb][r] = (colg <= rowg + r) ? e : 0.f;
          l[r] += p[kb][r];
        }
      } else {
        #pragma unroll
        for (int r = 0; r < 4; r++) {
          p[kb][r] = fast_exp2(fmaf(sc[r], SC2, -OFF));
          l[r] += p[kb][r];
        }
      }
    }

    // P: C-layout -> LDS (stride-64, XOR-chunk swizzled) -> A-layout frags
    #pragma unroll
    for (int kb = 0; kb < 4; kb++) {
      const int cb = kb * 2 + (lm >> 3), wi = lm & 7;
      #pragma unroll
      for (int r = 0; r < 4; r++) {
        const int prow = pxor + r;
        Pw[prow * 64 + ((cb ^ (prow & 7)) << 3) + wi] = (__bf16)p[kb][r];
      }
    }

    const bf16x8 ap0 = *(const bf16x8*)&Pw[lm * 64 + cpA];
    const bf16x8 ap1 = *(const bf16x8*)&Pw[lm * 64 + cpB];
    #pragma unroll
    for (int jb = 0; jb < 4; jb++) {
      const int vrow = (jb * 16 + lm) * 64;
      const bf16x8 bv0 = *(const bf16x8*)&Vc[vrow + cpA];
      const bf16x8 bv1 = *(const bf16x8*)&Vc[vrow + cpB];
      o[jb] = __builtin_amdgcn_mfma_f32_16x16x32_bf16(ap1, bv1,
              __builtin_amdgcn_mfma_f32_16x16x32_bf16(ap0, bv0, o[jb], 0, 0, 0), 0, 0, 0);
    }
  }

  const int b = bh >> 4, h = bh & 15;
  #pragma unroll
  for (int r = 0; r < 4; r++) {
    float lr = l[r];
    #pragma unroll
    for (int off = 8; off; off >>= 1) lr += __shfl_xor(lr, off);
    const float inv = 1.0f / lr;
    const size_t base = ((size_t)(b * S_LEN + rowg + r)) * D_DIM + h * 64;
    #pragma unroll
    for (int jb = 0; jb < 4; jb++)
      Ob[base + jb * 16 + lm] = (__bf16)(o[jb][r] * inv);
  }
}

extern "C" void kernel_launch(void* const* d_in, const int* in_sizes, int n_in,
                              void* d_out, int out_size, void* d_ws, size_t ws_size,
                              hipStream_t stream)
{
  (void)in_sizes; (void)n_in; (void)out_size; (void)ws_size;
  const float* x    = (const float*)d_in[0];
  const float* WQ   = (const float*)d_in[1];
  const float* WK   = (const float*)d_in[2];
  const float* WV   = (const float*)d_in[3];
  const float* WO   = (const float*)d_in[4];
  const float* gain = (const float*)d_in[5];
  const int* positions = (const int*)d_in[6];
  const int* theta     = (const int*)d_in[7];
  float* out = (float*)d_out;

  char* ws = (char*)d_ws;
  const size_t MB = 1024 * 1024;
  __bf16* xb  = (__bf16*)(ws + 0);        //  8 MB
  __bf16* WQb = (__bf16*)(ws + 8  * MB);  //  2 MB
  __bf16* WKb = (__bf16*)(ws + 10 * MB);  //  2 MB
  __bf16* WVb = (__bf16*)(ws + 12 * MB);  //  2 MB
  __bf16* WOb = (__bf16*)(ws + 14 * MB);  //  2 MB
  __bf16* Qfb = (__bf16*)(ws + 16 * MB);  //  8 MB  Q pre-norm bf16 [4096][1024]
  __bf16* Kfb = (__bf16*)(ws + 24 * MB);  //  8 MB
  __bf16* Vt  = (__bf16*)(ws + 32 * MB);  //  8 MB  [bh][64][s]  (direct from GEMM)
  __bf16* Qh  = (__bf16*)(ws + 40 * MB);  //  8 MB  [bh][s][64]
  __bf16* Kh  = (__bf16*)(ws + 48 * MB);  //  8 MB
  __bf16* Ob  = (__bf16*)(ws + 56 * MB);  //  8 MB  [b][s][1024]

  cast_all<<<1024, 256, 0, stream>>>(x, WQ, WK, WV, WO, xb, WQb, WKb, WVb, WOb);
  gemm_qkv<<<1536, 256, 0, stream>>>(xb, WQb, WKb, WVb, Qfb, Kfb, Vt);
  norm_rope<<<4096, 256, 0, stream>>>(Qfb, Kfb, gain, positions, theta, Qh, Kh);
  attn_fwd<<<1024, 256, 0, stream>>>(Qh, Kh, Vt, Ob);
  gemm_out32<<<1024, 256, 0, stream>>>(Ob, WOb, out);
}

// Round 10
// 179.821 us; speedup vs baseline: 1.0790x; 1.0184x over previous
//
#include <hip/hip_runtime.h>
#include <hip/hip_bf16.h>

typedef __attribute__((ext_vector_type(8))) __bf16 bf16x8;
typedef __attribute__((ext_vector_type(4))) __bf16 bf16x4;
typedef __attribute__((ext_vector_type(4))) float  f32x4;

#define S_LEN 2048
#define D_DIM 1024
#define NH    16
#define GK    1024
#define GN    1024

__device__ __forceinline__ float fast_exp2(float x) {
#if __has_builtin(__builtin_amdgcn_exp2f)
  return __builtin_amdgcn_exp2f(x);
#else
  return exp2f(x);
#endif
}

// async global->LDS, 16B per lane; HW scatters to wave-uniform-base + lane*16
__device__ __forceinline__ void gld_lds16(const void* g, void* l) {
  __builtin_amdgcn_global_load_lds(
      (const __attribute__((address_space(1))) unsigned int*)g,
      (__attribute__((address_space(3))) unsigned int*)l, 16, 0, 0);
}

// ---------------- fused fp32 -> bf16 cast, grid-stride ----------------
__global__ __launch_bounds__(256) void cast_all(
    const float* __restrict__ x,  const float* __restrict__ wq, const float* __restrict__ wk,
    const float* __restrict__ wv, const float* __restrict__ wo,
    __bf16* __restrict__ xb, __bf16* __restrict__ wqb, __bf16* __restrict__ wkb,
    __bf16* __restrict__ wvb, __bf16* __restrict__ wob)
{
  const int NTOT = 2 << 20;                      // 2M float4 chunks
  for (int i = blockIdx.x * 256 + threadIdx.x; i < NTOT; i += 1024 * 256) {
    const float* s; __bf16* d; int off;
    if (i < (1 << 20)) { s = x; d = xb; off = i; }
    else {
      const int j = i - (1 << 20);
      const int r = j >> 18; off = j & ((1 << 18) - 1);
      s = (r == 0) ? wq : (r == 1) ? wk : (r == 2) ? wv : wo;
      d = (r == 0) ? wqb : (r == 1) ? wkb : (r == 2) ? wvb : wob;
    }
    float4 v = ((const float4*)s)[off];
    bf16x4 o = { (__bf16)v.x, (__bf16)v.y, (__bf16)v.z, (__bf16)v.w };
    ((bf16x4*)d)[off] = o;
  }
}

// ---------------- QKV GEMM 64x128, BK=64, XCD-partitioned ----------------
__global__ __launch_bounds__(256, 6) void gemm_qkv(
    const __bf16* __restrict__ A,
    const __bf16* __restrict__ W0, const __bf16* __restrict__ W1, const __bf16* __restrict__ W2,
    __bf16* __restrict__ C0, __bf16* __restrict__ C1, __bf16* __restrict__ VtOut)
{
  const int bid = blockIdx.x;
  const int e = bid & 7, mg = e >> 1, ng = e & 1;
  const int q = bid >> 3;              // 0..191
  const int mode = q % 3;
  const int t = q / 3;                 // 0..63
  const int m0 = (mg * 16 + (t & 15)) * 64;
  const int n0 = (ng * 4 + (t >> 4)) * 128;
  const __bf16* Wm = (mode == 0) ? W0 : (mode == 1) ? W1 : W2;

  __shared__ __align__(16) __bf16 As[64 * 64];    //  8 KB
  __shared__ __align__(16) __bf16 Bs[128 * 64];   // 16 KB

  const int tid  = threadIdx.x;
  const int lane = tid & 63;
  const int w    = tid >> 6;
  const int wr   = w >> 1, wc = w & 1;
  const int lm   = lane & 15, qd = lane >> 4;

  const __bf16* ap[2]; int loA[2];
  #pragma unroll
  for (int j = 0; j < 2; j++) {
    const int c = tid + 256 * j;
    const int r = c >> 3, cpos = c & 7;
    ap[j] = A + (size_t)(m0 + r) * GK + (cpos ^ (r & 7)) * 8;
    loA[j] = c * 8;
  }
  const __bf16* bp[4]; int loB[4];
  #pragma unroll
  for (int j = 0; j < 4; j++) {
    const int c = tid + 256 * j;
    const int r = c >> 3, cpos = c & 7;
    bp[j] = Wm + (size_t)(n0 + r) * GK + (cpos ^ (r & 7)) * 8;
    loB[j] = c * 8;
  }

  const int sw = lm & 7;

  f32x4 zero = {0.f, 0.f, 0.f, 0.f};
  f32x4 acc[2][4];
  #pragma unroll
  for (int i = 0; i < 2; i++)
    #pragma unroll
    for (int j = 0; j < 4; j++) acc[i][j] = zero;

  for (int k0 = 0; k0 < GK; k0 += 64) {
    #pragma unroll
    for (int j = 0; j < 2; j++) gld_lds16(ap[j] + k0, &As[loA[j]]);
    #pragma unroll
    for (int j = 0; j < 4; j++) gld_lds16(bp[j] + k0, &Bs[loB[j]]);
    __syncthreads();
    #pragma unroll
    for (int half = 0; half < 2; half++) {
      const int cph = ((qd + 4 * half) ^ sw) * 8;
      bf16x8 af[2], bfv[4];
      #pragma unroll
      for (int i = 0; i < 2; i++) af[i]  = *(const bf16x8*)&As[(wr * 32 + i * 16 + lm) * 64 + cph];
      #pragma unroll
      for (int j = 0; j < 4; j++) bfv[j] = *(const bf16x8*)&Bs[(wc * 64 + j * 16 + lm) * 64 + cph];
      #pragma unroll
      for (int i = 0; i < 2; i++)
        #pragma unroll
        for (int j = 0; j < 4; j++)
          acc[i][j] = __builtin_amdgcn_mfma_f32_16x16x32_bf16(af[i], bfv[j], acc[i][j], 0, 0, 0);
    }
    __syncthreads();
  }

  if (mode < 2) {
    __bf16* C = (mode == 0) ? C0 : C1;
    #pragma unroll
    for (int i = 0; i < 2; i++) {
      const int row = m0 + wr * 32 + i * 16 + qd * 4;
      #pragma unroll
      for (int j = 0; j < 4; j++) {
        const int col = n0 + wc * 64 + j * 16 + lm;
        #pragma unroll
        for (int r = 0; r < 4; r++)
          C[(size_t)(row + r) * GN + col] = (__bf16)acc[i][j][r];
      }
    }
  } else {
    #pragma unroll
    for (int i = 0; i < 2; i++) {
      const int row = m0 + wr * 32 + i * 16 + qd * 4;    // token
      const int b = row >> 11, s = row & (S_LEN - 1);
      #pragma unroll
      for (int j = 0; j < 4; j++) {
        const int col = n0 + wc * 64 + j * 16 + lm;      // vdim
        const int h = col >> 6, d = col & 63;
        bf16x4 o = { (__bf16)acc[i][j][0], (__bf16)acc[i][j][1],
                     (__bf16)acc[i][j][2], (__bf16)acc[i][j][3] };
        *(bf16x4*)(VtOut + (((size_t)(b * NH + h) * 64 + d) * S_LEN + s)) = o;
      }
    }
  }
}

// ---------------- out-proj GEMM 64x128, BK=64, XCD-partitioned (fp32 out) ----------
// R6-proven shape: 512 blocks = 2/CU but 16 MFMA/wave/iter — best barrier amortization
// (R7/R8 showed both 128-row attn tiles and 32-row out tiles lose: occupancy x
// work-per-barrier has a sweet spot here).
__global__ __launch_bounds__(256, 6) void gemm_out64(
    const __bf16* __restrict__ A, const __bf16* __restrict__ Wm, float* __restrict__ C)
{
  const int bid = blockIdx.x;          // 512
  const int e = bid & 7, mg = e >> 1, ng = e & 1;
  const int q = bid >> 3;              // 0..63
  const int m0 = (mg * 16 + (q & 15)) * 64;
  const int n0 = (ng * 4 + (q >> 4)) * 128;

  __shared__ __align__(16) __bf16 As[64 * 64];    //  8 KB
  __shared__ __align__(16) __bf16 Bs[128 * 64];   // 16 KB

  const int tid  = threadIdx.x;
  const int lane = tid & 63;
  const int w    = tid >> 6;
  const int wr   = w >> 1, wc = w & 1;
  const int lm   = lane & 15, qd = lane >> 4;

  const __bf16* ap[2]; int loA[2];
  #pragma unroll
  for (int j = 0; j < 2; j++) {
    const int c = tid + 256 * j;
    const int r = c >> 3, cpos = c & 7;
    ap[j] = A + (size_t)(m0 + r) * GK + (cpos ^ (r & 7)) * 8;
    loA[j] = c * 8;
  }
  const __bf16* bp[4]; int loB[4];
  #pragma unroll
  for (int j = 0; j < 4; j++) {
    const int c = tid + 256 * j;
    const int r = c >> 3, cpos = c & 7;
    bp[j] = Wm + (size_t)(n0 + r) * GK + (cpos ^ (r & 7)) * 8;
    loB[j] = c * 8;
  }

  const int sw = lm & 7;

  f32x4 zero = {0.f, 0.f, 0.f, 0.f};
  f32x4 acc[2][4];
  #pragma unroll
  for (int i = 0; i < 2; i++)
    #pragma unroll
    for (int j = 0; j < 4; j++) acc[i][j] = zero;

  for (int k0 = 0; k0 < GK; k0 += 64) {
    #pragma unroll
    for (int j = 0; j < 2; j++) gld_lds16(ap[j] + k0, &As[loA[j]]);
    #pragma unroll
    for (int j = 0; j < 4; j++) gld_lds16(bp[j] + k0, &Bs[loB[j]]);
    __syncthreads();
    #pragma unroll
    for (int half = 0; half < 2; half++) {
      const int cph = ((qd + 4 * half) ^ sw) * 8;
      bf16x8 af[2], bfv[4];
      #pragma unroll
      for (int i = 0; i < 2; i++) af[i]  = *(const bf16x8*)&As[(wr * 32 + i * 16 + lm) * 64 + cph];
      #pragma unroll
      for (int j = 0; j < 4; j++) bfv[j] = *(const bf16x8*)&Bs[(wc * 64 + j * 16 + lm) * 64 + cph];
      #pragma unroll
      for (int i = 0; i < 2; i++)
        #pragma unroll
        for (int j = 0; j < 4; j++)
          acc[i][j] = __builtin_amdgcn_mfma_f32_16x16x32_bf16(af[i], bfv[j], acc[i][j], 0, 0, 0);
    }
    __syncthreads();
  }

  #pragma unroll
  for (int i = 0; i < 2; i++) {
    const int row = m0 + wr * 32 + i * 16 + qd * 4;
    #pragma unroll
    for (int j = 0; j < 4; j++) {
      const int col = n0 + wc * 64 + j * 16 + lm;
      #pragma unroll
      for (int r = 0; r < 4; r++)
        C[(size_t)(row + r) * GN + col] = acc[i][j][r];
    }
  }
}

// ---------------- RMSNorm + RoPE + head split (Q,K only; bf16 in) ----------------
// Q output is pre-scaled by SC2 = log2(e)/sqrt(64): attn then uses exp2(QK) with no
// fmaf and no offset (post-norm |score·SC2| <= ~11.6, safely in fp32/bf16 range).
__global__ __launch_bounds__(256) void norm_rope(
    const __bf16* __restrict__ Qf, const __bf16* __restrict__ Kf,
    const float* __restrict__ gain, const int* __restrict__ positions,
    const int* __restrict__ theta_p,
    __bf16* __restrict__ Qh, __bf16* __restrict__ Kh)
{
  const int row = blockIdx.x;             // b*S + s
  const int s = row & (S_LEN - 1), b = row >> 11;
  const int t = threadIdx.x, d0 = t * 4;

  const bf16x4 qv = *(const bf16x4*)(Qf + (size_t)row * D_DIM + d0);
  const bf16x4 kv = *(const bf16x4*)(Kf + (size_t)row * D_DIM + d0);
  const float q0 = (float)qv[0], q1 = (float)qv[1], q2 = (float)qv[2], q3 = (float)qv[3];
  const float k0 = (float)kv[0], k1 = (float)kv[1], k2 = (float)kv[2], k3 = (float)kv[3];

  float sq = q0 * q0 + q1 * q1 + q2 * q2 + q3 * q3;
  float sk = k0 * k0 + k1 * k1 + k2 * k2 + k3 * k3;
  #pragma unroll
  for (int off = 32; off; off >>= 1) { sq += __shfl_xor(sq, off); sk += __shfl_xor(sk, off); }
  __shared__ float red[8];
  const int lane = t & 63, wv = t >> 6;
  if (lane == 0) { red[wv] = sq; red[4 + wv] = sk; }
  __syncthreads();
  sq = red[0] + red[1] + red[2] + red[3];
  sk = red[4] + red[5] + red[6] + red[7];
  const float SC2 = 0.125f * 1.44269504089f;
  const float invq = rsqrtf(sq * (1.0f / 1024.0f) + 1e-5f) * SC2;   // fold score scale into Q
  const float invk = rsqrtf(sk * (1.0f / 1024.0f) + 1e-5f);

  const float4 g = *(const float4*)(gain + d0);
  const float qn0 = q0 * invq * g.x, qn1 = q1 * invq * g.y;
  const float qn2 = q2 * invq * g.z, qn3 = q3 * invq * g.w;
  const float kn0 = k0 * invk * g.x, kn1 = k1 * invk * g.y;
  const float kn2 = k2 * invk * g.z, kn3 = k3 * invk * g.w;

  const float pos = (float)positions[s];
  const float th  = (float)theta_p[0];
  const int idx = d0 & 63, h = d0 >> 6, p0 = idx >> 1;
  const float lg32 = __log2f(th) * (1.0f / 32.0f);
  const float f0 = fast_exp2(-(float)p0 * lg32);
  const float f1 = fast_exp2(-(float)(p0 + 1) * lg32);
  float s0, cc0, s1, cc1;
  __sincosf(pos * f0, &s0, &cc0);
  __sincosf(pos * f1, &s1, &cc1);

  const float qe0 = qn0 * cc0 - qn1 * s0, qo0 = qn1 * cc0 + qn0 * s0;
  const float qe1 = qn2 * cc1 - qn3 * s1, qo1 = qn3 * cc1 + qn2 * s1;
  const float ke0 = kn0 * cc0 - kn1 * s0, ko0 = kn1 * cc0 + kn0 * s0;
  const float ke1 = kn2 * cc1 - kn3 * s1, ko1 = kn3 * cc1 + kn2 * s1;

  const size_t obase = ((size_t)((b * NH + h) * S_LEN + s)) * 64 + idx;
  bf16x4 qo = { (__bf16)qe0, (__bf16)qo0, (__bf16)qe1, (__bf16)qo1 };
  bf16x4 ko = { (__bf16)ke0, (__bf16)ko0, (__bf16)ke1, (__bf16)ko1 };
  *(bf16x4*)(Qh + obase) = qo;
  *(bf16x4*)(Kh + obase) = ko;
}

// ---------------- causal flash attention, 1024 blocks @ 4/CU ----------------
// Q pre-scaled -> p = exp2(sc) directly (no fmaf/offset). Row-sum l computed by an
// extra ones-MFMA per k-half (l = P*1), killing 16 v_add/lane/tile and the epilogue
// shuffle reduce. VALU slots/lane/tile ~80 -> ~48.
__global__ __launch_bounds__(256) void attn_fwd(
    const __bf16* __restrict__ Qh, const __bf16* __restrict__ Kh,
    const __bf16* __restrict__ Vt, __bf16* __restrict__ Ob)
{
  const int bid = blockIdx.x;
  const int g   = bid >> 5, gj = g & 7, gs = g >> 3;
  const int qt  = (gs == 0) ? 31 - gj : (gs == 1) ? gj : (gs == 2) ? 23 - gj : 8 + gj;
  const int rr  = bid & 31;
  const int bh  = (rr & 7) * 4 + (rr >> 3);      // same-bh blocks -> same bid%8 (XCD)
  const int tid = threadIdx.x, lane = tid & 63, w = tid >> 6;
  const int lm = lane & 15, qd = lane >> 4;

  __shared__ __align__(16) __bf16 smem[8192 + 8192 + 4096];   // 40960 B
  __bf16* Ks = smem;                 // [2][4096]
  __bf16* Vs = smem + 8192;          // [2][4096]
  __bf16* Pw = smem + 16384 + w * 1024;

  const int row0 = qt * 64 + w * 16;
  const size_t qbase = (size_t)bh * S_LEN * 64;
  const bf16x8 aq0 = *(const bf16x8*)(Qh + qbase + (size_t)(row0 + lm) * 64 + qd * 8);
  const bf16x8 aq1 = *(const bf16x8*)(Qh + qbase + (size_t)(row0 + lm) * 64 + 32 + qd * 8);

  const __bf16* Kb = Kh + (size_t)bh * S_LEN * 64;
  const __bf16* Vb = Vt + (size_t)bh * 64 * S_LEN;
  const int c0 = tid, c1 = 256 + tid;
  const int kr0 = c0 >> 3, kr1 = c1 >> 3;
  const int kg0 = ((c0 & 7) ^ (kr0 & 7)) * 8;
  const int kg1 = ((c1 & 7) ^ (kr1 & 7)) * 8;
  const int cpA = (qd ^ (lm & 7)) * 8;
  const int cpB = cpA ^ 32;

  auto stage = [&](int buf, int k0) {
    __bf16* Kd = Ks + buf * 4096;
    __bf16* Vd = Vs + buf * 4096;
    gld_lds16(Kb + (size_t)(k0 + kr0) * 64 + kg0, &Kd[c0 * 8]);
    gld_lds16(Kb + (size_t)(k0 + kr1) * 64 + kg1, &Kd[c1 * 8]);
    gld_lds16(Vb + (size_t)kr0 * S_LEN + k0 + kg0, &Vd[c0 * 8]);
    gld_lds16(Vb + (size_t)kr1 * S_LEN + k0 + kg1, &Vd[c1 * 8]);
  };

  f32x4 zero = {0.f, 0.f, 0.f, 0.f};
  f32x4 lacc = zero;                 // row-sums via ones-MFMA (C-layout: lacc[r])
  f32x4 o[4];
  #pragma unroll
  for (int jb = 0; jb < 4; jb++) o[jb] = zero;

  bf16x8 ones;
  #pragma unroll
  for (int i = 0; i < 8; i++) ones[i] = (__bf16)1.0f;

  stage(0, 0);

  const int rowg = row0 + qd * 4;
  const int pxor = qd * 4;

  for (int kt = 0; kt <= qt; ++kt) {
    const int cur = kt & 1;
    __syncthreads();                 // buf[cur] staged; buf[cur^1] free
    if (kt < qt) stage(cur ^ 1, (kt + 1) * 64);

    const __bf16* Kc = Ks + cur * 4096;
    const __bf16* Vc = Vs + cur * 4096;
    const int k0 = kt * 64;

    float p[4][4];
    const bool diag = (kt == qt);
    #pragma unroll
    for (int kb = 0; kb < 4; kb++) {
      const int krow = (kb * 16 + lm) * 64;
      const bf16x8 bk0 = *(const bf16x8*)&Kc[krow + cpA];
      const bf16x8 bk1 = *(const bf16x8*)&Kc[krow + cpB];
      f32x4 sc = zero;
      sc = __builtin_amdgcn_mfma_f32_16x16x32_bf16(aq0, bk0, sc, 0, 0, 0);
      sc = __builtin_amdgcn_mfma_f32_16x16x32_bf16(aq1, bk1, sc, 0, 0, 0);
      if (diag) {
        const int colg = k0 + kb * 16 + lm;
        #pragma unroll
        for (int r = 0; r < 4; r++)
          p[kb][r] = (colg <= rowg + r) ? fast_exp2(sc[r]) : 0.f;
      } else {
        #pragma unroll
        for (int r = 0; r < 4; r++) p[kb][r] = fast_exp2(sc[r]);
      }
    }

    // P: C-layout -> LDS (stride-64, XOR-chunk swizzled) -> A-layout frags
    #pragma unroll
    for (int kb = 0; kb < 4; kb++) {
      const int cb = kb * 2 + (lm >> 3), wi = lm & 7;
      #pragma unroll
      for (int r = 0; r < 4; r++) {
        const int prow = pxor + r;
        Pw[prow * 64 + ((cb ^ (prow & 7)) << 3) + wi] = (__bf16)p[kb][r];
      }
    }

    const bf16x8 ap0 = *(const bf16x8*)&Pw[lm * 64 + cpA];
    const bf16x8 ap1 = *(const bf16x8*)&Pw[lm * 64 + cpB];
    // l += P * ones (row sums, C-layout — no per-lane adds, no epilogue shuffle)
    lacc = __builtin_amdgcn_mfma_f32_16x16x32_bf16(ap1, ones,
           __builtin_amdgcn_mfma_f32_16x16x32_bf16(ap0, ones, lacc, 0, 0, 0), 0, 0, 0);
    #pragma unroll
    for (int jb = 0; jb < 4; jb++) {
      const int vrow = (jb * 16 + lm) * 64;
      const bf16x8 bv0 = *(const bf16x8*)&Vc[vrow + cpA];
      const bf16x8 bv1 = *(const bf16x8*)&Vc[vrow + cpB];
      o[jb] = __builtin_amdgcn_mfma_f32_16x16x32_bf16(ap1, bv1,
              __builtin_amdgcn_mfma_f32_16x16x32_bf16(ap0, bv0, o[jb], 0, 0, 0), 0, 0, 0);
    }
  }

  const int b = bh >> 4, h = bh & 15;
  #pragma unroll
  for (int r = 0; r < 4; r++) {
    const float inv = 1.0f / lacc[r];
    const size_t base = ((size_t)(b * S_LEN + rowg + r)) * D_DIM + h * 64;
    #pragma unroll
    for (int jb = 0; jb < 4; jb++)
      Ob[base + jb * 16 + lm] = (__bf16)(o[jb][r] * inv);
  }
}

extern "C" void kernel_launch(void* const* d_in, const int* in_sizes, int n_in,
                              void* d_out, int out_size, void* d_ws, size_t ws_size,
                              hipStream_t stream)
{
  (void)in_sizes; (void)n_in; (void)out_size; (void)ws_size;
  const float* x    = (const float*)d_in[0];
  const float* WQ   = (const float*)d_in[1];
  const float* WK   = (const float*)d_in[2];
  const float* WV   = (const float*)d_in[3];
  const float* WO   = (const float*)d_in[4];
  const float* gain = (const float*)d_in[5];
  const int* positions = (const int*)d_in[6];
  const int* theta     = (const int*)d_in[7];
  float* out = (float*)d_out;

  char* ws = (char*)d_ws;
  const size_t MB = 1024 * 1024;
  __bf16* xb  = (__bf16*)(ws + 0);        //  8 MB
  __bf16* WQb = (__bf16*)(ws + 8  * MB);  //  2 MB
  __bf16* WKb = (__bf16*)(ws + 10 * MB);  //  2 MB
  __bf16* WVb = (__bf16*)(ws + 12 * MB);  //  2 MB
  __bf16* WOb = (__bf16*)(ws + 14 * MB);  //  2 MB
  __bf16* Qfb = (__bf16*)(ws + 16 * MB);  //  8 MB  Q pre-norm bf16 [4096][1024]
  __bf16* Kfb = (__bf16*)(ws + 24 * MB);  //  8 MB
  __bf16* Vt  = (__bf16*)(ws + 32 * MB);  //  8 MB  [bh][64][s]  (direct from GEMM)
  __bf16* Qh  = (__bf16*)(ws + 40 * MB);  //  8 MB  [bh][s][64]  (pre-scaled by SC2)
  __bf16* Kh  = (__bf16*)(ws + 48 * MB);  //  8 MB
  __bf16* Ob  = (__bf16*)(ws + 56 * MB);  //  8 MB  [b][s][1024]

  cast_all<<<1024, 256, 0, stream>>>(x, WQ, WK, WV, WO, xb, WQb, WKb, WVb, WOb);
  gemm_qkv<<<1536, 256, 0, stream>>>(xb, WQb, WKb, WVb, Qfb, Kfb, Vt);
  norm_rope<<<4096, 256, 0, stream>>>(Qfb, Kfb, gain, positions, theta, Qh, Kh);
  attn_fwd<<<1024, 256, 0, stream>>>(Qh, Kh, Vt, Ob);
  gemm_out64<<<512, 256, 0, stream>>>(Ob, WOb, out);
}

// Round 11
// 175.149 us; speedup vs baseline: 1.1078x; 1.0267x over previous
//
#include <hip/hip_runtime.h>
#include <hip/hip_bf16.h>

typedef __attribute__((ext_vector_type(8))) __bf16 bf16x8;
typedef __attribute__((ext_vector_type(4))) __bf16 bf16x4;
typedef __attribute__((ext_vector_type(4))) float  f32x4;
typedef __attribute__((ext_vector_type(4))) short  s16x4;

#define S_LEN 2048
#define D_DIM 1024
#define NH    16
#define GK    1024
#define GN    1024

__device__ __forceinline__ float fast_exp2(float x) {
#if __has_builtin(__builtin_amdgcn_exp2f)
  return __builtin_amdgcn_exp2f(x);
#else
  return exp2f(x);
#endif
}

// K=16 bf16 MFMA wrapper (builtin spelling differs across ROCm versions)
__device__ __forceinline__ f32x4 mfma16(bf16x4 a, bf16x4 b, f32x4 c) {
#if __has_builtin(__builtin_amdgcn_mfma_f32_16x16x16_bf16)
  return __builtin_amdgcn_mfma_f32_16x16x16_bf16(a, b, c, 0, 0, 0);
#else
  return __builtin_amdgcn_mfma_f32_16x16x16bf16_1k(
      __builtin_bit_cast(s16x4, a), __builtin_bit_cast(s16x4, b), c, 0, 0, 0);
#endif
}

// async global->LDS, 16B per lane; HW scatters to wave-uniform-base + lane*16
__device__ __forceinline__ void gld_lds16(const void* g, void* l) {
  __builtin_amdgcn_global_load_lds(
      (const __attribute__((address_space(1))) unsigned int*)g,
      (__attribute__((address_space(3))) unsigned int*)l, 16, 0, 0);
}

// ---------------- fused fp32 -> bf16 cast, grid-stride ----------------
__global__ __launch_bounds__(256) void cast_all(
    const float* __restrict__ x,  const float* __restrict__ wq, const float* __restrict__ wk,
    const float* __restrict__ wv, const float* __restrict__ wo,
    __bf16* __restrict__ xb, __bf16* __restrict__ wqb, __bf16* __restrict__ wkb,
    __bf16* __restrict__ wvb, __bf16* __restrict__ wob)
{
  const int NTOT = 2 << 20;                      // 2M float4 chunks
  for (int i = blockIdx.x * 256 + threadIdx.x; i < NTOT; i += 1024 * 256) {
    const float* s; __bf16* d; int off;
    if (i < (1 << 20)) { s = x; d = xb; off = i; }
    else {
      const int j = i - (1 << 20);
      const int r = j >> 18; off = j & ((1 << 18) - 1);
      s = (r == 0) ? wq : (r == 1) ? wk : (r == 2) ? wv : wo;
      d = (r == 0) ? wqb : (r == 1) ? wkb : (r == 2) ? wvb : wob;
    }
    float4 v = ((const float4*)s)[off];
    bf16x4 o = { (__bf16)v.x, (__bf16)v.y, (__bf16)v.z, (__bf16)v.w };
    ((bf16x4*)d)[off] = o;
  }
}

// ---------------- QKV GEMM 64x128, BK=64, XCD-partitioned ----------------
__global__ __launch_bounds__(256, 6) void gemm_qkv(
    const __bf16* __restrict__ A,
    const __bf16* __restrict__ W0, const __bf16* __restrict__ W1, const __bf16* __restrict__ W2,
    __bf16* __restrict__ C0, __bf16* __restrict__ C1, __bf16* __restrict__ VtOut)
{
  const int bid = blockIdx.x;
  const int e = bid & 7, mg = e >> 1, ng = e & 1;
  const int q = bid >> 3;              // 0..191
  const int mode = q % 3;
  const int t = q / 3;                 // 0..63
  const int m0 = (mg * 16 + (t & 15)) * 64;
  const int n0 = (ng * 4 + (t >> 4)) * 128;
  const __bf16* Wm = (mode == 0) ? W0 : (mode == 1) ? W1 : W2;

  __shared__ __align__(16) __bf16 As[64 * 64];    //  8 KB
  __shared__ __align__(16) __bf16 Bs[128 * 64];   // 16 KB

  const int tid  = threadIdx.x;
  const int lane = tid & 63;
  const int w    = tid >> 6;
  const int wr   = w >> 1, wc = w & 1;
  const int lm   = lane & 15, qd = lane >> 4;

  const __bf16* ap[2]; int loA[2];
  #pragma unroll
  for (int j = 0; j < 2; j++) {
    const int c = tid + 256 * j;
    const int r = c >> 3, cpos = c & 7;
    ap[j] = A + (size_t)(m0 + r) * GK + (cpos ^ (r & 7)) * 8;
    loA[j] = c * 8;
  }
  const __bf16* bp[4]; int loB[4];
  #pragma unroll
  for (int j = 0; j < 4; j++) {
    const int c = tid + 256 * j;
    const int r = c >> 3, cpos = c & 7;
    bp[j] = Wm + (size_t)(n0 + r) * GK + (cpos ^ (r & 7)) * 8;
    loB[j] = c * 8;
  }

  const int sw = lm & 7;

  f32x4 zero = {0.f, 0.f, 0.f, 0.f};
  f32x4 acc[2][4];
  #pragma unroll
  for (int i = 0; i < 2; i++)
    #pragma unroll
    for (int j = 0; j < 4; j++) acc[i][j] = zero;

  for (int k0 = 0; k0 < GK; k0 += 64) {
    #pragma unroll
    for (int j = 0; j < 2; j++) gld_lds16(ap[j] + k0, &As[loA[j]]);
    #pragma unroll
    for (int j = 0; j < 4; j++) gld_lds16(bp[j] + k0, &Bs[loB[j]]);
    __syncthreads();
    #pragma unroll
    for (int half = 0; half < 2; half++) {
      const int cph = ((qd + 4 * half) ^ sw) * 8;
      bf16x8 af[2], bfv[4];
      #pragma unroll
      for (int i = 0; i < 2; i++) af[i]  = *(const bf16x8*)&As[(wr * 32 + i * 16 + lm) * 64 + cph];
      #pragma unroll
      for (int j = 0; j < 4; j++) bfv[j] = *(const bf16x8*)&Bs[(wc * 64 + j * 16 + lm) * 64 + cph];
      #pragma unroll
      for (int i = 0; i < 2; i++)
        #pragma unroll
        for (int j = 0; j < 4; j++)
          acc[i][j] = __builtin_amdgcn_mfma_f32_16x16x32_bf16(af[i], bfv[j], acc[i][j], 0, 0, 0);
    }
    __syncthreads();
  }

  if (mode < 2) {
    __bf16* C = (mode == 0) ? C0 : C1;
    #pragma unroll
    for (int i = 0; i < 2; i++) {
      const int row = m0 + wr * 32 + i * 16 + qd * 4;
      #pragma unroll
      for (int j = 0; j < 4; j++) {
        const int col = n0 + wc * 64 + j * 16 + lm;
        #pragma unroll
        for (int r = 0; r < 4; r++)
          C[(size_t)(row + r) * GN + col] = (__bf16)acc[i][j][r];
      }
    }
  } else {
    #pragma unroll
    for (int i = 0; i < 2; i++) {
      const int row = m0 + wr * 32 + i * 16 + qd * 4;    // token
      const int b = row >> 11, s = row & (S_LEN - 1);
      #pragma unroll
      for (int j = 0; j < 4; j++) {
        const int col = n0 + wc * 64 + j * 16 + lm;      // vdim
        const int h = col >> 6, d = col & 63;
        bf16x4 o = { (__bf16)acc[i][j][0], (__bf16)acc[i][j][1],
                     (__bf16)acc[i][j][2], (__bf16)acc[i][j][3] };
        *(bf16x4*)(VtOut + (((size_t)(b * NH + h) * 64 + d) * S_LEN + s)) = o;
      }
    }
  }
}

// ---------------- out-proj GEMM 64x128, BK=64, XCD-partitioned (fp32 out) ----------
__global__ __launch_bounds__(256, 6) void gemm_out64(
    const __bf16* __restrict__ A, const __bf16* __restrict__ Wm, float* __restrict__ C)
{
  const int bid = blockIdx.x;          // 512
  const int e = bid & 7, mg = e >> 1, ng = e & 1;
  const int q = bid >> 3;              // 0..63
  const int m0 = (mg * 16 + (q & 15)) * 64;
  const int n0 = (ng * 4 + (q >> 4)) * 128;

  __shared__ __align__(16) __bf16 As[64 * 64];    //  8 KB
  __shared__ __align__(16) __bf16 Bs[128 * 64];   // 16 KB

  const int tid  = threadIdx.x;
  const int lane = tid & 63;
  const int w    = tid >> 6;
  const int wr   = w >> 1, wc = w & 1;
  const int lm   = lane & 15, qd = lane >> 4;

  const __bf16* ap[2]; int loA[2];
  #pragma unroll
  for (int j = 0; j < 2; j++) {
    const int c = tid + 256 * j;
    const int r = c >> 3, cpos = c & 7;
    ap[j] = A + (size_t)(m0 + r) * GK + (cpos ^ (r & 7)) * 8;
    loA[j] = c * 8;
  }
  const __bf16* bp[4]; int loB[4];
  #pragma unroll
  for (int j = 0; j < 4; j++) {
    const int c = tid + 256 * j;
    const int r = c >> 3, cpos = c & 7;
    bp[j] = Wm + (size_t)(n0 + r) * GK + (cpos ^ (r & 7)) * 8;
    loB[j] = c * 8;
  }

  const int sw = lm & 7;

  f32x4 zero = {0.f, 0.f, 0.f, 0.f};
  f32x4 acc[2][4];
  #pragma unroll
  for (int i = 0; i < 2; i++)
    #pragma unroll
    for (int j = 0; j < 4; j++) acc[i][j] = zero;

  for (int k0 = 0; k0 < GK; k0 += 64) {
    #pragma unroll
    for (int j = 0; j < 2; j++) gld_lds16(ap[j] + k0, &As[loA[j]]);
    #pragma unroll
    for (int j = 0; j < 4; j++) gld_lds16(bp[j] + k0, &Bs[loB[j]]);
    __syncthreads();
    #pragma unroll
    for (int half = 0; half < 2; half++) {
      const int cph = ((qd + 4 * half) ^ sw) * 8;
      bf16x8 af[2], bfv[4];
      #pragma unroll
      for (int i = 0; i < 2; i++) af[i]  = *(const bf16x8*)&As[(wr * 32 + i * 16 + lm) * 64 + cph];
      #pragma unroll
      for (int j = 0; j < 4; j++) bfv[j] = *(const bf16x8*)&Bs[(wc * 64 + j * 16 + lm) * 64 + cph];
      #pragma unroll
      for (int i = 0; i < 2; i++)
        #pragma unroll
        for (int j = 0; j < 4; j++)
          acc[i][j] = __builtin_amdgcn_mfma_f32_16x16x32_bf16(af[i], bfv[j], acc[i][j], 0, 0, 0);
    }
    __syncthreads();
  }

  #pragma unroll
  for (int i = 0; i < 2; i++) {
    const int row = m0 + wr * 32 + i * 16 + qd * 4;
    #pragma unroll
    for (int j = 0; j < 4; j++) {
      const int col = n0 + wc * 64 + j * 16 + lm;
      #pragma unroll
      for (int r = 0; r < 4; r++)
        C[(size_t)(row + r) * GN + col] = acc[i][j][r];
    }
  }
}

// ---------------- RMSNorm + RoPE + head split (Q,K only; bf16 in) ----------------
// Q output pre-scaled by SC2 = log2(e)/sqrt(64): attn uses exp2(QK) directly.
__global__ __launch_bounds__(256) void norm_rope(
    const __bf16* __restrict__ Qf, const __bf16* __restrict__ Kf,
    const float* __restrict__ gain, const int* __restrict__ positions,
    const int* __restrict__ theta_p,
    __bf16* __restrict__ Qh, __bf16* __restrict__ Kh)
{
  const int row = blockIdx.x;             // b*S + s
  const int s = row & (S_LEN - 1), b = row >> 11;
  const int t = threadIdx.x, d0 = t * 4;

  const bf16x4 qv = *(const bf16x4*)(Qf + (size_t)row * D_DIM + d0);
  const bf16x4 kv = *(const bf16x4*)(Kf + (size_t)row * D_DIM + d0);
  const float q0 = (float)qv[0], q1 = (float)qv[1], q2 = (float)qv[2], q3 = (float)qv[3];
  const float k0 = (float)kv[0], k1 = (float)kv[1], k2 = (float)kv[2], k3 = (float)kv[3];

  float sq = q0 * q0 + q1 * q1 + q2 * q2 + q3 * q3;
  float sk = k0 * k0 + k1 * k1 + k2 * k2 + k3 * k3;
  #pragma unroll
  for (int off = 32; off; off >>= 1) { sq += __shfl_xor(sq, off); sk += __shfl_xor(sk, off); }
  __shared__ float red[8];
  const int lane = t & 63, wv = t >> 6;
  if (lane == 0) { red[wv] = sq; red[4 + wv] = sk; }
  __syncthreads();
  sq = red[0] + red[1] + red[2] + red[3];
  sk = red[4] + red[5] + red[6] + red[7];
  const float SC2 = 0.125f * 1.44269504089f;
  const float invq = rsqrtf(sq * (1.0f / 1024.0f) + 1e-5f) * SC2;   // fold score scale into Q
  const float invk = rsqrtf(sk * (1.0f / 1024.0f) + 1e-5f);

  const float4 g = *(const float4*)(gain + d0);
  const float qn0 = q0 * invq * g.x, qn1 = q1 * invq * g.y;
  const float qn2 = q2 * invq * g.z, qn3 = q3 * invq * g.w;
  const float kn0 = k0 * invk * g.x, kn1 = k1 * invk * g.y;
  const float kn2 = k2 * invk * g.z, kn3 = k3 * invk * g.w;

  const float pos = (float)positions[s];
  const float th  = (float)theta_p[0];
  const int idx = d0 & 63, h = d0 >> 6, p0 = idx >> 1;
  const float lg32 = __log2f(th) * (1.0f / 32.0f);
  const float f0 = fast_exp2(-(float)p0 * lg32);
  const float f1 = fast_exp2(-(float)(p0 + 1) * lg32);
  float s0, cc0, s1, cc1;
  __sincosf(pos * f0, &s0, &cc0);
  __sincosf(pos * f1, &s1, &cc1);

  const float qe0 = qn0 * cc0 - qn1 * s0, qo0 = qn1 * cc0 + qn0 * s0;
  const float qe1 = qn2 * cc1 - qn3 * s1, qo1 = qn3 * cc1 + qn2 * s1;
  const float ke0 = kn0 * cc0 - kn1 * s0, ko0 = kn1 * cc0 + kn0 * s0;
  const float ke1 = kn2 * cc1 - kn3 * s1, ko1 = kn3 * cc1 + kn2 * s1;

  const size_t obase = ((size_t)((b * NH + h) * S_LEN + s)) * 64 + idx;
  bf16x4 qo = { (__bf16)qe0, (__bf16)qo0, (__bf16)qe1, (__bf16)qo1 };
  bf16x4 ko = { (__bf16)ke0, (__bf16)ko0, (__bf16)ke1, (__bf16)ko1 };
  *(bf16x4*)(Qh + obase) = qo;
  *(bf16x4*)(Kh + obase) = ko;
}

// ---------------- causal flash attention, S^T formulation (no P LDS round-trip) ----
// Swapped QK MFMA operands give S^T in C-layout: lane holds S^T[key=qd*4+r][q=lm].
// That row map equals the K=16 MFMA B-fragment k-map, so exp2'd P^T feeds PV
// (O^T = V^T x P^T, A-frags = 8B LDS reads of Vs) and the ones-row-sum entirely
// in-register. Epilogue: O^T C-layout -> 4 contiguous bf16x4 stores. LDS 32 KB.
__global__ __launch_bounds__(256) void attn_fwd(
    const __bf16* __restrict__ Qh, const __bf16* __restrict__ Kh,
    const __bf16* __restrict__ Vt, __bf16* __restrict__ Ob)
{
  const int bid = blockIdx.x;
  const int g   = bid >> 5, gj = g & 7, gs = g >> 3;
  const int qt  = (gs == 0) ? 31 - gj : (gs == 1) ? gj : (gs == 2) ? 23 - gj : 8 + gj;
  const int rr  = bid & 31;
  const int bh  = (rr & 7) * 4 + (rr >> 3);      // same-bh blocks -> same bid%8 (XCD)
  const int tid = threadIdx.x, lane = tid & 63, w = tid >> 6;
  const int lm = lane & 15, qd = lane >> 4;

  __shared__ __align__(16) __bf16 smem[8192 + 8192];   // 32768 B
  __bf16* Ks = smem;                 // [2][4096]
  __bf16* Vs = smem + 8192;          // [2][4096]

  const int row0 = qt * 64 + w * 16;
  const int qglob = row0 + lm;                   // this lane's query row
  const size_t qbase = (size_t)bh * S_LEN * 64;
  const bf16x8 aq0 = *(const bf16x8*)(Qh + qbase + (size_t)qglob * 64 + qd * 8);
  const bf16x8 aq1 = *(const bf16x8*)(Qh + qbase + (size_t)qglob * 64 + 32 + qd * 8);

  const __bf16* Kb = Kh + (size_t)bh * S_LEN * 64;
  const __bf16* Vb = Vt + (size_t)bh * 64 * S_LEN;
  const int c0 = tid, c1 = 256 + tid;
  const int kr0 = c0 >> 3, kr1 = c1 >> 3;
  const int kg0 = ((c0 & 7) ^ (kr0 & 7)) * 8;
  const int kg1 = ((c1 & 7) ^ (kr1 & 7)) * 8;
  const int cpA = (qd ^ (lm & 7)) * 8;
  const int cpB = cpA ^ 32;

  auto stage = [&](int buf, int k0) {
    __bf16* Kd = Ks + buf * 4096;
    __bf16* Vd = Vs + buf * 4096;
    gld_lds16(Kb + (size_t)(k0 + kr0) * 64 + kg0, &Kd[c0 * 8]);
    gld_lds16(Kb + (size_t)(k0 + kr1) * 64 + kg1, &Kd[c1 * 8]);
    gld_lds16(Vb + (size_t)kr0 * S_LEN + k0 + kg0, &Vd[c0 * 8]);
    gld_lds16(Vb + (size_t)kr1 * S_LEN + k0 + kg1, &Vd[c1 * 8]);
  };

  f32x4 zero = {0.f, 0.f, 0.f, 0.f};
  f32x4 lacc = zero;                 // all 4 regs hold l[q=lm]
  f32x4 o[4];                        // o[jb][r] = O^T[d = jb*16+qd*4+r][q=lm]
  #pragma unroll
  for (int jb = 0; jb < 4; jb++) o[jb] = zero;

  bf16x4 ones4;
  #pragma unroll
  for (int i = 0; i < 4; i++) ones4[i] = (__bf16)1.0f;

  stage(0, 0);

  for (int kt = 0; kt <= qt; ++kt) {
    const int cur = kt & 1;
    __syncthreads();                 // buf[cur] staged; buf[cur^1] free
    if (kt < qt) stage(cur ^ 1, (kt + 1) * 64);

    const __bf16* Kc = Ks + cur * 4096;
    const __bf16* Vc = Vs + cur * 4096;
    const int k0 = kt * 64;
    const bool diag = (kt == qt);

    bf16x4 pfrag[4];
    #pragma unroll
    for (int kb = 0; kb < 4; kb++) {
      const int krow = (kb * 16 + lm) * 64;
      const bf16x8 ak0 = *(const bf16x8*)&Kc[krow + cpA];
      const bf16x8 ak1 = *(const bf16x8*)&Kc[krow + cpB];
      f32x4 sc = zero;                                   // S^T: A=K, B=Q
      sc = __builtin_amdgcn_mfma_f32_16x16x32_bf16(ak0, aq0, sc, 0, 0, 0);
      sc = __builtin_amdgcn_mfma_f32_16x16x32_bf16(ak1, aq1, sc, 0, 0, 0);
      float p[4];
      if (diag) {
        const int keyb = k0 + kb * 16 + qd * 4;
        #pragma unroll
        for (int r = 0; r < 4; r++)
          p[r] = (keyb + r <= qglob) ? fast_exp2(sc[r]) : 0.f;
      } else {
        #pragma unroll
        for (int r = 0; r < 4; r++) p[r] = fast_exp2(sc[r]);
      }
      bf16x4 pf = { (__bf16)p[0], (__bf16)p[1], (__bf16)p[2], (__bf16)p[3] };
      pfrag[kb] = pf;
      lacc = mfma16(ones4, pf, lacc);                    // l[q] partial row-sums
    }

    // PV: O^T[d][q] += V^T[d][key] P^T[key][q], K=16 chunks, B = pfrag in-register
    #pragma unroll
    for (int jb = 0; jb < 4; jb++) {
      const int vrow = jb * 16 + lm;
      const int rsw = vrow & 7;
      #pragma unroll
      for (int kb = 0; kb < 4; kb++) {
        const int c = 2 * kb + (qd >> 1);
        const bf16x4 av = *(const bf16x4*)&Vc[vrow * 64 + ((c ^ rsw) << 3) + (qd & 1) * 4];
        o[jb] = mfma16(av, pfrag[kb], o[jb]);
      }
    }
  }

  const int b = bh >> 4, h = bh & 15;
  const float inv = 1.0f / lacc[0];
  const size_t base = ((size_t)(b * S_LEN + qglob)) * D_DIM + h * 64 + qd * 4;
  #pragma unroll
  for (int jb = 0; jb < 4; jb++) {
    bf16x4 ov = { (__bf16)(o[jb][0] * inv), (__bf16)(o[jb][1] * inv),
                  (__bf16)(o[jb][2] * inv), (__bf16)(o[jb][3] * inv) };
    *(bf16x4*)(Ob + base + jb * 16) = ov;
  }
}

extern "C" void kernel_launch(void* const* d_in, const int* in_sizes, int n_in,
                              void* d_out, int out_size, void* d_ws, size_t ws_size,
                              hipStream_t stream)
{
  (void)in_sizes; (void)n_in; (void)out_size; (void)ws_size;
  const float* x    = (const float*)d_in[0];
  const float* WQ   = (const float*)d_in[1];
  const float* WK   = (const float*)d_in[2];
  const float* WV   = (const float*)d_in[3];
  const float* WO   = (const float*)d_in[4];
  const float* gain = (const float*)d_in[5];
  const int* positions = (const int*)d_in[6];
  const int* theta     = (const int*)d_in[7];
  float* out = (float*)d_out;

  char* ws = (char*)d_ws;
  const size_t MB = 1024 * 1024;
  __bf16* xb  = (__bf16*)(ws + 0);        //  8 MB
  __bf16* WQb = (__bf16*)(ws + 8  * MB);  //  2 MB
  __bf16* WKb = (__bf16*)(ws + 10 * MB);  //  2 MB
  __bf16* WVb = (__bf16*)(ws + 12 * MB);  //  2 MB
  __bf16* WOb = (__bf16*)(ws + 14 * MB);  //  2 MB
  __bf16* Qfb = (__bf16*)(ws + 16 * MB);  //  8 MB  Q pre-norm bf16 [4096][1024]
  __bf16* Kfb = (__bf16*)(ws + 24 * MB);  //  8 MB
  __bf16* Vt  = (__bf16*)(ws + 32 * MB);  //  8 MB  [bh][64][s]  (direct from GEMM)
  __bf16* Qh  = (__bf16*)(ws + 40 * MB);  //  8 MB  [bh][s][64]  (pre-scaled by SC2)
  __bf16* Kh  = (__bf16*)(ws + 48 * MB);  //  8 MB
  __bf16* Ob  = (__bf16*)(ws + 56 * MB);  //  8 MB  [b][s][1024]

  cast_all<<<1024, 256, 0, stream>>>(x, WQ, WK, WV, WO, xb, WQb, WKb, WVb, WOb);
  gemm_qkv<<<1536, 256, 0, stream>>>(xb, WQb, WKb, WVb, Qfb, Kfb, Vt);
  norm_rope<<<4096, 256, 0, stream>>>(Qfb, Kfb, gain, positions, theta, Qh, Kh);
  attn_fwd<<<1024, 256, 0, stream>>>(Qh, Kh, Vt, Ob);
  gemm_out64<<<512, 256, 0, stream>>>(Ob, WOb, out);
}